// Round 14
// baseline (126.713 us; speedup 1.0000x reference)
//
#include <hip/hip_runtime.h>
#include <hip/hip_bf16.h>

typedef __bf16 bf16x8 __attribute__((ext_vector_type(8)));
typedef __bf16 bf16x4 __attribute__((ext_vector_type(4)));
typedef float  f32x4  __attribute__((ext_vector_type(4)));

constexpr int NN = 16384;
constexpr int EE = 64;
constexpr int DD = 128;
constexpr int EG  = 8;     // experts per block

// ---------- pre-pass 1: X f32 -> bf16 row-major [N][D] ----------
__global__ __launch_bounds__(256)
void cvt_x(const float* __restrict__ X, __bf16* __restrict__ Xb) {
    int i = blockIdx.x * 256 + threadIdx.x;
    const float4* src = (const float4*)X;
    float4 v0 = src[2*i], v1 = src[2*i+1];
    bf16x8 p;
    p[0]=(__bf16)v0.x; p[1]=(__bf16)v0.y; p[2]=(__bf16)v0.z; p[3]=(__bf16)v0.w;
    p[4]=(__bf16)v1.x; p[5]=(__bf16)v1.y; p[6]=(__bf16)v1.z; p[7]=(__bf16)v1.w;
    ((bf16x8*)Xb)[i] = p;
}

// ---------- pre-pass 2: W[e][d][f] f32 -> BLOCKED bf16 layout WB ----------
// WB[e][s(8)][kk(4)][lane(64)][16B]: lane (l15,kg) holds f = s*16+l15,
// d = kk*32+kg*8 .. +7. One 1 KB chunk per (s,kk) = exactly one coalesced
// 64-lane global load in the GEMM (b-fragment load order).
__global__ __launch_bounds__(256)
void cvt_wt(const float* __restrict__ W, __bf16* __restrict__ WB) {
    __shared__ __bf16 T[DD][DD + 1];
    const int e = blockIdx.x;
    const int t = threadIdx.x;
    const float4* Wg = (const float4*)(W + (size_t)e * DD * DD);
    #pragma unroll
    for (int i = 0; i < 16; ++i) {
        int ft = i * 256 + t;
        int d = ft >> 5, f0 = (ft & 31) * 4;
        float4 v = Wg[ft];
        T[f0+0][d] = (__bf16)v.x;
        T[f0+1][d] = (__bf16)v.y;
        T[f0+2][d] = (__bf16)v.z;
        T[f0+3][d] = (__bf16)v.w;
    }
    __syncthreads();
    __bf16* out = WB + (size_t)e * DD * DD;   // 16384 bf16 per expert
    #pragma unroll
    for (int i = 0; i < 8; ++i) {
        int o = i * 256 + t;                  // 0..2047 chunk index
        int s    = o >> 8;
        int kk   = (o >> 6) & 3;
        int lane = o & 63;
        int l15 = lane & 15, kg = lane >> 4;
        int f  = s*16 + l15;
        int d0 = kk*32 + kg*8;
        bf16x8 p;
        #pragma unroll
        for (int j = 0; j < 8; ++j) p[j] = T[f][d0 + j];
        *(bf16x8*)(out + o * 8) = p;
    }
}

// ---------- main GEMM: W in REGISTERS, barrier-free loop ----------
// 512 thr / 8 waves; block = 128 rows x 8 experts. Wave (wr,wc) = 32 rows x
// 64 cols. b-fragments (16 x bf16x8 = 64 VGPR) live in regs, double-buffered
// across experts (named arrays via inlined lambda -> no scratch). No LDS for
// W, no glls, NO barriers in the loop: obuf is wave-private, bias via LDS.
// Stores drain continuously; compiler emits counted vmcnt for b consumption.
__global__ __launch_bounds__(512, 2)
void experts_gemm_rb(const __bf16* __restrict__ Xb,
                     const __bf16* __restrict__ WB,
                     const float* __restrict__ Bias,
                     float* __restrict__ O)
{
    __shared__ __align__(16) char lds[65536 + 4096];   // obuf 8x8KB | bias 4KB
    const int t    = threadIdx.x;
    const int lane = t & 63, w = t >> 6;
    const int l15  = lane & 15, kg = lane >> 4;
    const int wr   = w >> 1, wc = w & 1;
    const int eg   = blockIdx.x & (EE/EG - 1);
    const int n0   = (blockIdx.x >> 3) * 128;
    const int e0   = eg * EG;
    char* obuf = lds + w * 8192;               // wave-private 8 KB
    char* blds = lds + 65536;                  // 8 experts x 512 B bias

    // X fragments, loaded once
    bf16x8 a[2][4];
    {
        const __bf16* Xp = Xb + (size_t)(n0 + wr*32 + l15) * DD + kg*8;
        #pragma unroll
        for (int m = 0; m < 2; ++m)
            #pragma unroll
            for (int kk = 0; kk < 4; ++kk)
                a[m][kk] = *(const bf16x8*)(Xp + m*16*DD + kk*32);
    }

    // bias for all EG experts -> LDS (lgkm-only consumption in the loop)
    if (t < 256) {
        f32x4 v = ((const f32x4*)(Bias + e0*DD))[t];
        *(f32x4*)(blds + t*16) = v;
    }

    auto load_b = [&](bf16x8 (&bf)[16], int e) {
        const char* src = (const char*)WB + (size_t)e * 32768 + lane*16;
        #pragma unroll
        for (int n = 0; n < 4; ++n)
            #pragma unroll
            for (int kk = 0; kk < 4; ++kk)
                bf[n*4+kk] = *(const bf16x8*)(src + (wc*4+n)*4096 + kk*1024);
    };

    bf16x8 bA[16], bB[16];
    load_b(bA, e0);
    __syncthreads();   // bias visibility (prologue only)

    auto body = [&](bf16x8 (&bc)[16], bf16x8 (&bn)[16], int ei) {
        const int e = e0 + ei;
        // prefetch next expert's b-frags FIRST (overlap with this compute)
        if (ei + 1 < EG) load_b(bn, e + 1);

        // acc init = bias via LDS
        f32x4 acc[2][4];
        #pragma unroll
        for (int n = 0; n < 4; ++n) {
            f32x4 bv = *(const f32x4*)(blds + ei*512 + wc*256 + n*64 + kg*16);
            acc[0][n] = bv; acc[1][n] = bv;
        }

        // compute (all-register operands; waits only on bc's loads from the
        // previous body — oldest in vm queue, stores keep draining)
        #pragma unroll
        for (int kk = 0; kk < 4; ++kk)
            #pragma unroll
            for (int m = 0; m < 2; ++m)
                #pragma unroll
                for (int n = 0; n < 4; ++n)
                    acc[m][n] = __builtin_amdgcn_mfma_f32_16x16x32_bf16(
                        bc[n*4+kk], a[m][kk], acc[m][n], 0, 0, 0);

        // stage acc -> wave-private obuf (row = m*16+l15, 256 B/row)
        #pragma unroll
        for (int m = 0; m < 2; ++m)
            #pragma unroll
            for (int n = 0; n < 4; ++n) {
                int row = m*16 + l15;
                int off = row*256 + n*64 + kg*16;
                off ^= (row & 7) << 4;
                *(f32x4*)(obuf + off) = acc[m][n];
            }

        // readback + 256 B-contiguous stores (4 rows x 16 lanes x 16 B /inst)
        {
            const int ro = lane >> 4, c16 = lane & 15;
            #pragma unroll
            for (int rg = 0; rg < 8; ++rg) {
                int row = rg*4 + ro;
                int off = row*256 + c16*16;
                off ^= (row & 7) << 4;
                f32x4 v = *(const f32x4*)(obuf + off);
                *(f32x4*)(O + (size_t)(n0 + wr*32 + row) * (EE*DD)
                            + e*DD + wc*64 + c16*4) = v;
            }
        }
    };

    body(bA, bB, 0); body(bB, bA, 1); body(bA, bB, 2); body(bB, bA, 3);
    body(bA, bB, 4); body(bB, bA, 5); body(bA, bB, 6); body(bB, bA, 7);
}

// ---------- fallback (round-0 kernel, used if ws too small) ----------
__global__ __launch_bounds__(256, 2)
void experts_gemm_fb(const float* __restrict__ X,
                     const float* __restrict__ W,
                     const float* __restrict__ Bias,
                     float* __restrict__ O)
{
    constexpr int BM = 128;
    __shared__ __align__(16) char lds[BM*DD*2 + DD*DD*2];
    __bf16* As = (__bf16*)lds;
    __bf16* Bs = (__bf16*)(lds + BM*DD*2);

    const int t   = threadIdx.x;
    const int e   = blockIdx.x & (EE - 1);
    const int n0  = (blockIdx.x >> 6) * BM;

    {
        const float4* Xg = (const float4*)(X + (size_t)n0 * DD);
        #pragma unroll
        for (int i = 0; i < 16; ++i) {
            int ft = i * 256 + t;
            float4 v = Xg[ft];
            int n = ft >> 5, d0 = (ft & 31) << 2;
            bf16x4 p;
            p[0]=(__bf16)v.x; p[1]=(__bf16)v.y; p[2]=(__bf16)v.z; p[3]=(__bf16)v.w;
            int off = n * 256 + d0 * 2;
            off ^= (n & 7) << 4;
            *(bf16x4*)((char*)As + off) = p;
        }
    }
    {
        const float4* Wg = (const float4*)(W + (size_t)e * DD * DD);
        #pragma unroll
        for (int i = 0; i < 4; ++i) {
            int bb = i * 256 + t;
            int db = bb >> 5, fb = bb & 31;
            float4 r0 = Wg[(db*4+0)*32 + fb];
            float4 r1 = Wg[(db*4+1)*32 + fb];
            float4 r2 = Wg[(db*4+2)*32 + fb];
            float4 r3 = Wg[(db*4+3)*32 + fb];
            const float* q0=(const float*)&r0; const float* q1=(const float*)&r1;
            const float* q2=(const float*)&r2; const float* q3=(const float*)&r3;
            #pragma unroll
            for (int j = 0; j < 4; ++j) {
                bf16x4 p;
                p[0]=(__bf16)q0[j]; p[1]=(__bf16)q1[j];
                p[2]=(__bf16)q2[j]; p[3]=(__bf16)q3[j];
                int f = fb * 4 + j;
                int off = f * 256 + db * 8;
                off ^= (f & 7) << 4;
                *(bf16x4*)((char*)Bs + off) = p;
            }
        }
    }
    __syncthreads();

    const int lane = t & 63, w = t >> 6;
    const int wr = w >> 1, wc = w & 1;
    const int l15 = lane & 15, kg = lane >> 4;

    f32x4 acc[4][4];
    #pragma unroll
    for (int m = 0; m < 4; ++m)
        #pragma unroll
        for (int n = 0; n < 4; ++n) {
            acc[m][n][0]=0.f; acc[m][n][1]=0.f; acc[m][n][2]=0.f; acc[m][n][3]=0.f;
        }

    float bias[4];
    #pragma unroll
    for (int n = 0; n < 4; ++n) bias[n] = Bias[e*DD + wc*64 + n*16 + l15];

    #pragma unroll
    for (int kk = 0; kk < 4; ++kk) {
        int koff = kk * 32 + kg * 8;
        bf16x8 av[4], bvv[4];
        #pragma unroll
        for (int m = 0; m < 4; ++m) {
            int row = wr*64 + m*16 + l15;
            int off = row * 256 + koff * 2;
            off ^= (row & 7) << 4;
            av[m] = *(const bf16x8*)((const char*)As + off);
        }
        #pragma unroll
        for (int n = 0; n < 4; ++n) {
            int col = wc*64 + n*16 + l15;
            int off = col * 256 + koff * 2;
            off ^= (col & 7) << 4;
            bvv[n] = *(const bf16x8*)((const char*)Bs + off);
        }
        #pragma unroll
        for (int m = 0; m < 4; ++m)
            #pragma unroll
            for (int n = 0; n < 4; ++n)
                acc[m][n] = __builtin_amdgcn_mfma_f32_16x16x32_bf16(
                    av[m], bvv[n], acc[m][n], 0, 0, 0);
    }

    float* Op = O + (size_t)n0 * (EE*DD) + (size_t)e * DD;
    #pragma unroll
    for (int m = 0; m < 4; ++m)
        #pragma unroll
        for (int n = 0; n < 4; ++n) {
            int cg = wc*64 + n*16 + l15;
            #pragma unroll
            for (int r = 0; r < 4; ++r) {
                int rg = wr*64 + m*16 + kg*4 + r;
                Op[(size_t)rg * (EE*DD) + cg] = acc[m][n][r] + bias[n];
            }
        }
}

extern "C" void kernel_launch(void* const* d_in, const int* in_sizes, int n_in,
                              void* d_out, int out_size, void* d_ws, size_t ws_size,
                              hipStream_t stream) {
    const float* X = (const float*)d_in[0];
    const float* W = (const float*)d_in[1];
    const float* B = (const float*)d_in[2];
    float* O = (float*)d_out;

    const size_t xb_bytes = (size_t)NN * DD * sizeof(__bf16);      // 4 MiB
    const size_t wt_bytes = (size_t)EE * DD * DD * sizeof(__bf16); // 2 MiB

    if (ws_size >= xb_bytes + wt_bytes) {
        __bf16* Xb = (__bf16*)d_ws;
        __bf16* WB = (__bf16*)((char*)d_ws + xb_bytes);
        cvt_x<<<NN * DD / 8 / 256, 256, 0, stream>>>(X, Xb);
        cvt_wt<<<EE, 256, 0, stream>>>(W, WB);
        experts_gemm_rb<<<(NN / 128) * (EE / EG), 512, 0, stream>>>(Xb, WB, B, O);
    } else {
        experts_gemm_fb<<<(NN / 128) * EE, 256, 0, stream>>>(X, W, B, O);
    }
}